// Round 5
// baseline (153.241 us; speedup 1.0000x reference)
//
#include <hip/hip_runtime.h>
#include <math.h>

#define HD 512
#define BB 4
#define TT 128
#define SS 512
#define CEXP 2.88539008177792681f   // 2*log2(e)

typedef __attribute__((ext_vector_type(8))) short short8;
typedef __attribute__((ext_vector_type(4))) float floatx4;
typedef unsigned short ushort_t;
typedef unsigned int uint_t;

__device__ __forceinline__ float tanh_e(float x) {
    float t = __builtin_amdgcn_rcpf(__expf(2.f * x) + 1.f);
    return fmaf(-2.f, t, 1.f);
}
__device__ __forceinline__ ushort_t f2bf(float x) {      // RNE fp32->bf16
    unsigned int u = __float_as_uint(x);
    u += 0x7fffu + ((u >> 16) & 1u);
    return (ushort_t)(u >> 16);
}

// ---------------- Kernel 0: weight transpose/cast bf16 [n][k] + query cast + v prep ----------
__global__ __launch_bounds__(256) void wtrans_kernel(
    const float* __restrict__ Ws, const float* __restrict__ Wh,
    const float* __restrict__ Wo, const float* __restrict__ query,
    const float* __restrict__ v,
    ushort_t* __restrict__ Ts, ushort_t* __restrict__ Th, ushort_t* __restrict__ To,
    ushort_t* __restrict__ cq, float* __restrict__ wneg, float* __restrict__ vsum4)
{
    const int bid = blockIdx.x;
    if (bid < 1024) {
        const float* src; ushort_t* dst; int K, N, l;
        if (bid < 256)      { src = Ws; dst = Ts; K = 512;  N = 512; l = bid; }
        else if (bid < 512) { src = Wh; dst = Th; K = 512;  N = 512; l = bid - 256; }
        else                { src = Wo; dst = To; K = 1024; N = 512; l = bid - 512; }
        const int tk = l % (K / 32), tn = l / (K / 32);
        const int k0 = tk * 32, n0 = tn * 32;

        __shared__ ushort_t tile[32][36];
        const int r  = threadIdx.x >> 3;
        const int c4 = (threadIdx.x & 7) * 4;

        float4 s = *(const float4*)(src + (size_t)(k0 + r) * N + n0 + c4);
        tile[r][c4 + 0] = f2bf(s.x);
        tile[r][c4 + 1] = f2bf(s.y);
        tile[r][c4 + 2] = f2bf(s.z);
        tile[r][c4 + 3] = f2bf(s.w);
        __syncthreads();
        ushort4 o;
        o.x = tile[c4 + 0][r];
        o.y = tile[c4 + 1][r];
        o.z = tile[c4 + 2][r];
        o.w = tile[c4 + 3][r];
        *(ushort4*)&dst[(size_t)(n0 + r) * K + k0 + c4] = o;
    } else if (bid < 1152) {
        // query -> bf16 into cq[m][512 + h]
        const int idx = ((bid - 1024) * 256 + threadIdx.x) * 8;   // 0..262136
        const int m = idx >> 9, h = idx & 511;
        float4 q0 = *(const float4*)(query + (size_t)m * HD + h);
        float4 q1 = *(const float4*)(query + (size_t)m * HD + h + 4);
        uint4 o;
        o.x = (uint_t)f2bf(q0.x) | ((uint_t)f2bf(q0.y) << 16);
        o.y = (uint_t)f2bf(q0.z) | ((uint_t)f2bf(q0.w) << 16);
        o.z = (uint_t)f2bf(q1.x) | ((uint_t)f2bf(q1.y) << 16);
        o.w = (uint_t)f2bf(q1.z) | ((uint_t)f2bf(q1.w) << 16);
        *(uint4*)&cq[(size_t)m * 1024 + 512 + h] = o;
    } else {
        // wneg = -2v; vsum4[q] = sum of v over quarter q
        const int tid = threadIdx.x;
        wneg[tid]       = -2.f * v[tid];
        wneg[256 + tid] = -2.f * v[256 + tid];
        const int w = tid >> 6, lane = tid & 63;
        float sv = v[w * 128 + lane] + v[w * 128 + 64 + lane];
        #pragma unroll
        for (int off = 32; off; off >>= 1) sv += __shfl_xor(sv, off, 64);
        if (lane == 0) vsum4[w] = sv;
    }
}

// ---------------- Kernel 1: MFMA proj: pq2 = CEXP*(q@W_s), peT = bf16(CEXP*(enc@W_h)^T) -------
#define LDP 40   // padded bf16 row stride for [row][k(32)] tiles
__global__ __launch_bounds__(256) void proj_kernel(
    const float* __restrict__ query, const float* __restrict__ enc,
    const ushort_t* __restrict__ WTs, const ushort_t* __restrict__ WTh,
    float* __restrict__ pq2, ushort_t* __restrict__ peT)
{
    const int bm = blockIdx.x;            // 0..39: 8 query tiles, 32 enc tiles
    const int bn = blockIdx.y;            // 0..7
    const bool isQ = (bm < 8);
    const float* A = isQ ? query : enc;
    const ushort_t* WT = isQ ? WTs : WTh;
    const int m0 = (isQ ? bm : bm - 8) * 64;
    const int n0 = bn * 64;

    __shared__ ushort_t As[64 * LDP];     // [m][k]
    __shared__ ushort_t Bs[64 * LDP];     // [n][k]

    const int tid = threadIdx.x;
    const int lane = tid & 63, w = tid >> 6;
    const int quad = lane >> 4, lrow = lane & 15;
    const int mw = (w & 1) * 32, nw = (w >> 1) * 32;

    const int ar = tid >> 2;              // 0..63
    const int ac = (tid & 3) * 8;         // 0,8,16,24

    floatx4 zero = {0.f, 0.f, 0.f, 0.f};
    floatx4 acc[2][2] = {{zero, zero}, {zero, zero}};

    float4 a0 = *(const float4*)(A + (size_t)(m0 + ar) * HD + ac);
    float4 a1 = *(const float4*)(A + (size_t)(m0 + ar) * HD + ac + 4);
    uint4  bld = *(const uint4*)&WT[(size_t)(n0 + ar) * HD + ac];

    for (int k0 = 0; k0 < HD; k0 += 32) {
        __syncthreads();
        uint4 ap;
        ap.x = (uint_t)f2bf(a0.x) | ((uint_t)f2bf(a0.y) << 16);
        ap.y = (uint_t)f2bf(a0.z) | ((uint_t)f2bf(a0.w) << 16);
        ap.z = (uint_t)f2bf(a1.x) | ((uint_t)f2bf(a1.y) << 16);
        ap.w = (uint_t)f2bf(a1.z) | ((uint_t)f2bf(a1.w) << 16);
        *(uint4*)&As[ar * LDP + ac] = ap;
        *(uint4*)&Bs[ar * LDP + ac] = bld;
        __syncthreads();
        if (k0 + 32 < HD) {
            a0  = *(const float4*)(A + (size_t)(m0 + ar) * HD + k0 + 32 + ac);
            a1  = *(const float4*)(A + (size_t)(m0 + ar) * HD + k0 + 32 + ac + 4);
            bld = *(const uint4*)&WT[(size_t)(n0 + ar) * HD + k0 + 32 + ac];
        }
        short8 af[2], bf[2];
        #pragma unroll
        for (int i = 0; i < 2; ++i)
            af[i] = *(const short8*)&As[(mw + i * 16 + lrow) * LDP + quad * 8];
        #pragma unroll
        for (int j = 0; j < 2; ++j)
            bf[j] = *(const short8*)&Bs[(nw + j * 16 + lrow) * LDP + quad * 8];
        #pragma unroll
        for (int i = 0; i < 2; ++i)
            #pragma unroll
            for (int j = 0; j < 2; ++j)
                acc[i][j] = __builtin_amdgcn_mfma_f32_16x16x32_bf16(af[i], bf[j], acc[i][j], 0, 0, 0);
    }

    if (isQ) {
        #pragma unroll
        for (int i = 0; i < 2; ++i)
            #pragma unroll
            for (int j = 0; j < 2; ++j)
                #pragma unroll
                for (int r = 0; r < 4; ++r) {
                    const int row = m0 + mw + i * 16 + quad * 4 + r;
                    const int col = n0 + nw + j * 16 + lrow;
                    pq2[(size_t)row * HD + col] = CEXP * acc[i][j][r];
                }
    } else {
        #pragma unroll
        for (int i = 0; i < 2; ++i)
            #pragma unroll
            for (int j = 0; j < 2; ++j) {
                const int gm = m0 + mw + i * 16 + quad * 4;   // enc-local row (4 consecutive)
                const int b = gm >> 9, s = gm & 511;
                const int col = n0 + nw + j * 16 + lrow;
                ushort4 o;
                o.x = f2bf(CEXP * acc[i][j][0]);
                o.y = f2bf(CEXP * acc[i][j][1]);
                o.z = f2bf(CEXP * acc[i][j][2]);
                o.w = f2bf(CEXP * acc[i][j][3]);
                *(ushort4*)&peT[((size_t)b * HD + col) * SS + s] = o;
            }
    }
}

// ---------------- Kernel 2: partial scores, grid (B*T, 4), 256 threads x 2 s ----------------
// All per-h operands (pq2, wneg) are wave-uniform -> SGPR loads; inner loop is
// add / exp / add1 / rcp / fmac per element.
__global__ __launch_bounds__(256) void score_part_kernel(
    const float* __restrict__ pq2, const ushort_t* __restrict__ peT,
    const float* __restrict__ wneg, const float* __restrict__ vsum4,
    const int* __restrict__ lens, _Float16* __restrict__ sp)
{
    const int bt = blockIdx.x;
    const int hq = blockIdx.y;
    const int b = bt >> 7;
    const int tid = threadIdx.x;
    const int h0 = hq * 128;

    const float sumv = vsum4[hq];
    const float* aptr = pq2 + (size_t)bt * HD + h0;
    const float* wptr = wneg + h0;

    const int len = lens[b];
    const int s0 = tid * 2;
    if (s0 >= len) return;

    const ushort_t* col = peT + ((size_t)b * HD + h0) * SS + s0;
    float acc0 = 0.f, acc1 = 0.f;
    #pragma unroll 8
    for (int h = 0; h < 128; ++h) {
        uint_t p = *(const uint_t*)(col + (size_t)h * SS);
        const float a = aptr[h];          // SGPR
        const float w = wptr[h];          // SGPR
        float pl = __uint_as_float(p << 16);
        float ph = __uint_as_float(p & 0xffff0000u);
        float t0 = __builtin_amdgcn_rcpf(exp2f(pl + a) + 1.f);
        float t1 = __builtin_amdgcn_rcpf(exp2f(ph + a) + 1.f);
        acc0 = fmaf(w, t0, acc0);
        acc1 = fmaf(w, t1, acc1);
    }
    _Float16 f0 = (_Float16)(sumv + acc0);
    _Float16 f1 = (_Float16)(sumv + acc1);
    uint_t pk = (uint_t)*(ushort_t*)&f0 | ((uint_t)*(ushort_t*)&f1 << 16);
    *(uint_t*)(sp + ((size_t)hq * (BB * TT) + bt) * SS + s0) = pk;
}

// ---------------- Kernel 3: combine partials + masked softmax -> alpha (zeros past len) --------
__global__ __launch_bounds__(512) void combine_kernel(
    const _Float16* __restrict__ sp, const int* __restrict__ lens,
    float* __restrict__ alpha)
{
    const int bt = blockIdx.x;
    const int b = bt >> 7;
    const int tid = threadIdx.x;
    const int wave = tid >> 6;
    __shared__ float s_red[16];

    const int len = lens[b];
    float sc = -INFINITY;
    if (tid < len) {
        const size_t i = (size_t)bt * SS + tid;
        const size_t st = (size_t)BB * TT * SS;
        sc = (float)sp[i] + (float)sp[i + st] + (float)sp[i + 2 * st] + (float)sp[i + 3 * st];
    }
    float m = sc;
    #pragma unroll
    for (int off = 32; off; off >>= 1) m = fmaxf(m, __shfl_xor(m, off, 64));
    if ((tid & 63) == 0) s_red[wave] = m;
    __syncthreads();
    m = s_red[0];
    #pragma unroll
    for (int w2 = 1; w2 < 8; ++w2) m = fmaxf(m, s_red[w2]);

    float e = (tid < len) ? __expf(sc - m) : 0.f;
    float sum = e;
    #pragma unroll
    for (int off = 32; off; off >>= 1) sum += __shfl_xor(sum, off, 64);
    if ((tid & 63) == 0) s_red[8 + wave] = sum;
    __syncthreads();
    float total = s_red[8];
    #pragma unroll
    for (int w2 = 1; w2 < 8; ++w2) total += s_red[8 + w2];

    alpha[(size_t)bt * SS + tid] = e * __builtin_amdgcn_rcpf(total);
}

// ---------------- Kernel 4: ctx = alpha @ enc via MFMA, bf16 out into cq[:, 0:512] ------------
#define LDA_A 40
#define LDA_B 76
__global__ __launch_bounds__(256) void ctx_kernel(
    const float* __restrict__ alpha, const float* __restrict__ enc,
    const int* __restrict__ lens, ushort_t* __restrict__ cq)
{
    const int b = blockIdx.x;
    const int t0 = blockIdx.y * 16;
    const int h0 = blockIdx.z * 64;
    __shared__ ushort_t sA[16 * LDA_A];   // [t][s]
    __shared__ ushort_t sB[32 * LDA_B];   // [s][h]  (natural; frag reads strided)
    const int tid = threadIdx.x;
    const int lane = tid & 63, w = tid >> 6;
    const int quad = lane >> 4, lrow = lane & 15;
    const int nw = w * 16;
    const int len = lens[b];

    const int ar  = tid >> 4;          // 0..15  (t)
    const int ac2 = (tid & 15) * 2;    // 0..30  (s pair)
    const int br  = tid >> 3;          // 0..31  (s)
    const int bc8 = (tid & 7) * 8;     // h offset

    floatx4 acc = {0.f, 0.f, 0.f, 0.f};

    for (int s0 = 0; s0 < len; s0 += 32) {
        __syncthreads();
        {
            float2 a2 = *(const float2*)(alpha + (size_t)(b * TT + t0 + ar) * SS + s0 + ac2);
            uint_t pk = (uint_t)f2bf(a2.x) | ((uint_t)f2bf(a2.y) << 16);
            *(uint_t*)&sA[ar * LDA_A + ac2] = pk;
            const float* erow = enc + (size_t)(b * SS + s0 + br) * HD + h0 + bc8;
            float4 e0 = *(const float4*)erow;
            float4 e1 = *(const float4*)(erow + 4);
            uint2 w0, w1;
            w0.x = (uint_t)f2bf(e0.x) | ((uint_t)f2bf(e0.y) << 16);
            w0.y = (uint_t)f2bf(e0.z) | ((uint_t)f2bf(e0.w) << 16);
            w1.x = (uint_t)f2bf(e1.x) | ((uint_t)f2bf(e1.y) << 16);
            w1.y = (uint_t)f2bf(e1.z) | ((uint_t)f2bf(e1.w) << 16);
            *(uint2*)&sB[br * LDA_B + bc8] = w0;
            *(uint2*)&sB[br * LDA_B + bc8 + 4] = w1;
        }
        __syncthreads();
        short8 af = *(const short8*)&sA[lrow * LDA_A + quad * 8];
        short8 bf;
        #pragma unroll
        for (int j = 0; j < 8; ++j)
            bf[j] = (short)sB[(quad * 8 + j) * LDA_B + nw + lrow];
        acc = __builtin_amdgcn_mfma_f32_16x16x32_bf16(af, bf, acc, 0, 0, 0);
    }
    #pragma unroll
    for (int r = 0; r < 4; ++r)
        cq[(size_t)(b * TT + t0 + quad * 4 + r) * 1024 + h0 + nw + lrow] = f2bf(acc[r]);
}

// ---------------- Kernel 5: out = tanh(cq @ WTo^T), MFMA, 32x64 tiles ----------------
__global__ __launch_bounds__(256) void out_kernel(
    const ushort_t* __restrict__ cq, const ushort_t* __restrict__ WTo,
    float* __restrict__ out)
{
    const int m0 = blockIdx.x * 32;
    const int n0 = blockIdx.y * 64;

    __shared__ ushort_t As[32 * LDP];     // [m][k]
    __shared__ ushort_t Bs[64 * LDP];     // [n][k]

    const int tid = threadIdx.x;
    const int lane = tid & 63, w = tid >> 6;
    const int quad = lane >> 4, lrow = lane & 15;
    const int mw = (w & 1) * 16, nw = (w >> 1) * 32;

    const int ar = tid >> 3, ac4 = (tid & 7) * 4;   // A: uint2 (4 u16)
    const int br = tid >> 2, bc8 = (tid & 3) * 8;   // B: uint4 (8 u16)

    floatx4 zero = {0.f, 0.f, 0.f, 0.f};
    floatx4 acc[2] = {zero, zero};

    uint2 av = *(const uint2*)&cq[(size_t)(m0 + ar) * 1024 + ac4];
    uint4 bv = *(const uint4*)&WTo[(size_t)(n0 + br) * 1024 + bc8];

    for (int k0 = 0; k0 < 1024; k0 += 32) {
        __syncthreads();
        *(uint2*)&As[ar * LDP + ac4] = av;
        *(uint4*)&Bs[br * LDP + bc8] = bv;
        __syncthreads();
        if (k0 + 32 < 1024) {
            av = *(const uint2*)&cq[(size_t)(m0 + ar) * 1024 + k0 + 32 + ac4];
            bv = *(const uint4*)&WTo[(size_t)(n0 + br) * 1024 + k0 + 32 + bc8];
        }
        short8 af = *(const short8*)&As[(mw + lrow) * LDP + quad * 8];
        #pragma unroll
        for (int j = 0; j < 2; ++j) {
            short8 bf8 = *(const short8*)&Bs[(nw + j * 16 + lrow) * LDP + quad * 8];
            acc[j] = __builtin_amdgcn_mfma_f32_16x16x32_bf16(af, bf8, acc[j], 0, 0, 0);
        }
    }
    #pragma unroll
    for (int j = 0; j < 2; ++j)
        #pragma unroll
        for (int r = 0; r < 4; ++r) {
            const int row = m0 + mw + quad * 4 + r;
            const int col = n0 + nw + j * 16 + lrow;
            out[(size_t)row * HD + col] = tanh_e(acc[j][r]);
        }
}

extern "C" void kernel_launch(void* const* d_in, const int* in_sizes, int n_in,
                              void* d_out, int out_size, void* d_ws, size_t ws_size,
                              hipStream_t stream) {
    (void)in_sizes; (void)n_in; (void)out_size; (void)ws_size;
    const float* query = (const float*)d_in[0];   // (B,T,H)
    const float* enc   = (const float*)d_in[1];   // (B,S,H)
    const int*   lens  = (const int*)d_in[2];     // (B,)
    const float* W_h   = (const float*)d_in[3];   // (H,H)
    const float* W_s   = (const float*)d_in[4];   // (H,H)
    const float* v     = (const float*)d_in[5];   // (H,)
    const float* W_out = (const float*)d_in[6];   // (2H,H)
    float* out = (float*)d_out;

    // workspace layout (~9.5 MB)
    ushort_t* WTs   = (ushort_t*)d_ws;                          // 512 KB
    ushort_t* WTh   = WTs + (size_t)HD * HD;                    // 512 KB
    ushort_t* WTo   = WTh + (size_t)HD * HD;                    // 1 MB
    float*    pq2   = (float*)(WTo + (size_t)HD * 2 * HD);      // 1 MB (CEXP-scaled)
    ushort_t* peT   = (ushort_t*)(pq2 + (size_t)BB * TT * HD);  // 2 MB (bf16, CEXP-scaled)
    _Float16* sp    = (_Float16*)(peT + (size_t)BB * HD * SS);  // 2 MB (fp16 partials)
    float*    alpha = (float*)(sp + (size_t)4 * BB * TT * SS);  // 1 MB
    ushort_t* cq    = (ushort_t*)(alpha + (size_t)BB * TT * SS);// 1 MB ([ctx|q] bf16)
    float*    wneg  = (float*)(cq + (size_t)BB * TT * 1024);    // 2 KB (-2v)
    float*    vsum4 = wneg + 512;                               // 16 B

    wtrans_kernel<<<dim3(1153), 256, 0, stream>>>(W_s, W_h, W_out, query, v,
                                                  WTs, WTh, WTo, cq, wneg, vsum4);
    proj_kernel<<<dim3(40, 8), 256, 0, stream>>>(query, enc, WTs, WTh, pq2, peT);
    score_part_kernel<<<dim3(BB * TT, 4), 256, 0, stream>>>(pq2, peT, wneg, vsum4, lens, sp);
    combine_kernel<<<dim3(BB * TT), 512, 0, stream>>>(sp, lens, alpha);
    ctx_kernel<<<dim3(BB, TT / 16, HD / 64), 256, 0, stream>>>(alpha, enc, lens, cq);
    out_kernel<<<dim3(16, 8), 256, 0, stream>>>(cq, WTo, out);
}

// Round 6
// 128.716 us; speedup vs baseline: 1.1905x; 1.1905x over previous
//
#include <hip/hip_runtime.h>
#include <math.h>

#define HD 512
#define BB 4
#define TT 128
#define SS 512

typedef __attribute__((ext_vector_type(8))) short short8;
typedef __attribute__((ext_vector_type(4))) float floatx4;
typedef unsigned short ushort_t;
typedef unsigned int uint_t;

__device__ __forceinline__ float tanh_e(float x) {
    float t = __builtin_amdgcn_rcpf(__expf(2.f * x) + 1.f);
    return fmaf(-2.f, t, 1.f);
}
__device__ __forceinline__ ushort_t f2bf(float x) {      // RNE fp32->bf16
    unsigned int u = __float_as_uint(x);
    u += 0x7fffu + ((u >> 16) & 1u);
    return (ushort_t)(u >> 16);
}

// ---- Kernel 0: weight transpose/cast bf16 [n][k]; query->cq right half; enc->bf16 ----
__global__ __launch_bounds__(256) void wtrans_kernel(
    const float* __restrict__ Ws, const float* __restrict__ Wh,
    const float* __restrict__ Wo, const float* __restrict__ query,
    const float* __restrict__ enc,
    ushort_t* __restrict__ Ts, ushort_t* __restrict__ Th, ushort_t* __restrict__ To,
    ushort_t* __restrict__ cq, ushort_t* __restrict__ encB)
{
    const int bid = blockIdx.x;
    if (bid < 1024) {
        const float* src; ushort_t* dst; int K, N, l;
        if (bid < 256)      { src = Ws; dst = Ts; K = 512;  N = 512; l = bid; }
        else if (bid < 512) { src = Wh; dst = Th; K = 512;  N = 512; l = bid - 256; }
        else                { src = Wo; dst = To; K = 1024; N = 512; l = bid - 512; }
        const int tk = l % (K / 32), tn = l / (K / 32);
        const int k0 = tk * 32, n0 = tn * 32;

        __shared__ ushort_t tile[32][36];
        const int r  = threadIdx.x >> 3;
        const int c4 = (threadIdx.x & 7) * 4;

        float4 s = *(const float4*)(src + (size_t)(k0 + r) * N + n0 + c4);
        tile[r][c4 + 0] = f2bf(s.x);
        tile[r][c4 + 1] = f2bf(s.y);
        tile[r][c4 + 2] = f2bf(s.z);
        tile[r][c4 + 3] = f2bf(s.w);
        __syncthreads();
        ushort4 o;
        o.x = tile[c4 + 0][r];
        o.y = tile[c4 + 1][r];
        o.z = tile[c4 + 2][r];
        o.w = tile[c4 + 3][r];
        *(ushort4*)&dst[(size_t)(n0 + r) * K + k0 + c4] = o;
    } else if (bid < 1152) {
        // query -> bf16 into cq[m][512 + h]  (also serves as proj A for the q-path)
        const int idx = ((bid - 1024) * 256 + threadIdx.x) * 8;
        const int m = idx >> 9, h = idx & 511;
        float4 q0 = *(const float4*)(query + (size_t)m * HD + h);
        float4 q1 = *(const float4*)(query + (size_t)m * HD + h + 4);
        uint4 o;
        o.x = (uint_t)f2bf(q0.x) | ((uint_t)f2bf(q0.y) << 16);
        o.y = (uint_t)f2bf(q0.z) | ((uint_t)f2bf(q0.w) << 16);
        o.z = (uint_t)f2bf(q1.x) | ((uint_t)f2bf(q1.y) << 16);
        o.w = (uint_t)f2bf(q1.z) | ((uint_t)f2bf(q1.w) << 16);
        *(uint4*)&cq[(size_t)m * 1024 + 512 + h] = o;
    } else {
        // enc -> bf16 encB (row-major, same layout)
        const size_t idx = ((size_t)(bid - 1152) * 256 + threadIdx.x) * 8;
        float4 e0 = *(const float4*)(enc + idx);
        float4 e1 = *(const float4*)(enc + idx + 4);
        uint4 o;
        o.x = (uint_t)f2bf(e0.x) | ((uint_t)f2bf(e0.y) << 16);
        o.y = (uint_t)f2bf(e0.z) | ((uint_t)f2bf(e0.w) << 16);
        o.z = (uint_t)f2bf(e1.x) | ((uint_t)f2bf(e1.y) << 16);
        o.w = (uint_t)f2bf(e1.z) | ((uint_t)f2bf(e1.w) << 16);
        *(uint4*)&encB[idx] = o;
    }
}

// ---- Kernel 1: MFMA proj. q-path: tqa = {tanh(pq), v*tanh(pq)} fp32.
//                           enc-path: peT = fp16(tanh(pe))^T per batch (B,H,S). ----
#define LDP 40   // padded bf16 row stride for [row][k(32)] tiles
__global__ __launch_bounds__(256) void proj_kernel(
    const ushort_t* __restrict__ cq, const ushort_t* __restrict__ encB,
    const ushort_t* __restrict__ WTs, const ushort_t* __restrict__ WTh,
    const float* __restrict__ v,
    float2* __restrict__ tqa, _Float16* __restrict__ peT)
{
    const int bm = blockIdx.x;            // 0..39: 8 query tiles, 32 enc tiles
    const int bn = blockIdx.y;            // 0..7
    const bool isQ = (bm < 8);
    const ushort_t* A = isQ ? (cq + 512) : encB;
    const int lda = isQ ? 1024 : 512;
    const ushort_t* WT = isQ ? WTs : WTh;
    const int m0 = (isQ ? bm : bm - 8) * 64;
    const int n0 = bn * 64;

    __shared__ ushort_t As[64 * LDP];     // [m][k]
    __shared__ ushort_t Bs[64 * LDP];     // [n][k]

    const int tid = threadIdx.x;
    const int lane = tid & 63, w = tid >> 6;
    const int quad = lane >> 4, lrow = lane & 15;
    const int mw = (w & 1) * 32, nw = (w >> 1) * 32;

    const int ar = tid >> 2;              // 0..63
    const int ac = (tid & 3) * 8;         // 0,8,16,24

    floatx4 zero = {0.f, 0.f, 0.f, 0.f};
    floatx4 acc[2][2] = {{zero, zero}, {zero, zero}};

    uint4 ald = *(const uint4*)&A[(size_t)(m0 + ar) * lda + ac];
    uint4 bld = *(const uint4*)&WT[(size_t)(n0 + ar) * HD + ac];

    for (int k0 = 0; k0 < HD; k0 += 32) {
        __syncthreads();
        *(uint4*)&As[ar * LDP + ac] = ald;
        *(uint4*)&Bs[ar * LDP + ac] = bld;
        __syncthreads();
        if (k0 + 32 < HD) {
            ald = *(const uint4*)&A[(size_t)(m0 + ar) * lda + k0 + 32 + ac];
            bld = *(const uint4*)&WT[(size_t)(n0 + ar) * HD + k0 + 32 + ac];
        }
        short8 af[2], bf[2];
        #pragma unroll
        for (int i = 0; i < 2; ++i)
            af[i] = *(const short8*)&As[(mw + i * 16 + lrow) * LDP + quad * 8];
        #pragma unroll
        for (int j = 0; j < 2; ++j)
            bf[j] = *(const short8*)&Bs[(nw + j * 16 + lrow) * LDP + quad * 8];
        #pragma unroll
        for (int i = 0; i < 2; ++i)
            #pragma unroll
            for (int j = 0; j < 2; ++j)
                acc[i][j] = __builtin_amdgcn_mfma_f32_16x16x32_bf16(af[i], bf[j], acc[i][j], 0, 0, 0);
    }

    if (isQ) {
        #pragma unroll
        for (int j = 0; j < 2; ++j) {
            const int col = n0 + nw + j * 16 + lrow;
            const float vj = v[col];
            #pragma unroll
            for (int i = 0; i < 2; ++i)
                #pragma unroll
                for (int r = 0; r < 4; ++r) {
                    const int row = m0 + mw + i * 16 + quad * 4 + r;
                    float tq = tanh_e(acc[i][j][r]);
                    float2 o; o.x = tq; o.y = vj * tq;
                    tqa[(size_t)row * HD + col] = o;
                }
        }
    } else {
        #pragma unroll
        for (int i = 0; i < 2; ++i)
            #pragma unroll
            for (int j = 0; j < 2; ++j) {
                const int gm = m0 + mw + i * 16 + quad * 4;   // enc-local row (4 consecutive s)
                const int b = gm >> 9, s = gm & 511;
                const int col = n0 + nw + j * 16 + lrow;
                _Float16 t0 = (_Float16)tanh_e(acc[i][j][0]);
                _Float16 t1 = (_Float16)tanh_e(acc[i][j][1]);
                _Float16 t2 = (_Float16)tanh_e(acc[i][j][2]);
                _Float16 t3 = (_Float16)tanh_e(acc[i][j][3]);
                ushort4 o;
                o.x = *(ushort_t*)&t0; o.y = *(ushort_t*)&t1;
                o.z = *(ushort_t*)&t2; o.w = *(ushort_t*)&t3;
                *(ushort4*)((ushort_t*)peT + ((size_t)b * HD + col) * SS + s) = o;
            }
    }
}

// ---- Kernel 2: partial scores via tanh addition formula — no transcendentals.
//      score_term = v*(Tq+Te)/(1+Tq*Te).  grid (B*T, 4), 256 thr x 2 s. ----
__global__ __launch_bounds__(256) void score_part_kernel(
    const float2* __restrict__ tqa, const _Float16* __restrict__ peT,
    const float* __restrict__ vv, const int* __restrict__ lens,
    _Float16* __restrict__ sp)
{
    const int bt = blockIdx.x;
    const int hq = blockIdx.y;
    const int b = bt >> 7;
    const int tid = threadIdx.x;
    const int h0 = hq * 128;

    const int len = lens[b];
    const int s0 = tid * 2;
    if (s0 >= len) return;

    const float2* qa = tqa + (size_t)bt * HD + h0;       // wave-uniform -> SGPR
    const float* vp = vv + h0;                           // wave-uniform -> SGPR
    const ushort_t* col = (const ushort_t*)peT + ((size_t)b * HD + h0) * SS + s0;

    float acc0 = 0.f, acc1 = 0.f;
    #pragma unroll 8
    for (int h = 0; h < 128; ++h) {
        uint_t p = *(const uint_t*)(col + (size_t)h * SS);
        const float2 q = qa[h];
        const float vh = vp[h];
        ushort_t plo = (ushort_t)p, phi = (ushort_t)(p >> 16);
        float te0 = (float)*(_Float16*)&plo;
        float te1 = (float)*(_Float16*)&phi;
        float d0 = fmaf(q.x, te0, 1.f);
        float d1 = fmaf(q.x, te1, 1.f);
        float m0 = fmaf(vh, te0, q.y);
        float m1 = fmaf(vh, te1, q.y);
        acc0 = fmaf(m0, __builtin_amdgcn_rcpf(d0), acc0);
        acc1 = fmaf(m1, __builtin_amdgcn_rcpf(d1), acc1);
    }
    _Float16 f0 = (_Float16)acc0;
    _Float16 f1 = (_Float16)acc1;
    uint_t pk = (uint_t)*(ushort_t*)&f0 | ((uint_t)*(ushort_t*)&f1 << 16);
    *(uint_t*)(sp + ((size_t)hq * (BB * TT) + bt) * SS + s0) = pk;
}

// ---- Kernel 3: combine partials + masked softmax -> alpha (zeros past len) ----
__global__ __launch_bounds__(512) void combine_kernel(
    const _Float16* __restrict__ sp, const int* __restrict__ lens,
    float* __restrict__ alpha)
{
    const int bt = blockIdx.x;
    const int b = bt >> 7;
    const int tid = threadIdx.x;
    const int wave = tid >> 6;
    __shared__ float s_red[16];

    const int len = lens[b];
    float sc = -INFINITY;
    if (tid < len) {
        const size_t i = (size_t)bt * SS + tid;
        const size_t st = (size_t)BB * TT * SS;
        sc = (float)sp[i] + (float)sp[i + st] + (float)sp[i + 2 * st] + (float)sp[i + 3 * st];
    }
    float m = sc;
    #pragma unroll
    for (int off = 32; off; off >>= 1) m = fmaxf(m, __shfl_xor(m, off, 64));
    if ((tid & 63) == 0) s_red[wave] = m;
    __syncthreads();
    m = s_red[0];
    #pragma unroll
    for (int w2 = 1; w2 < 8; ++w2) m = fmaxf(m, s_red[w2]);

    float e = (tid < len) ? __expf(sc - m) : 0.f;
    float sum = e;
    #pragma unroll
    for (int off = 32; off; off >>= 1) sum += __shfl_xor(sum, off, 64);
    if ((tid & 63) == 0) s_red[8 + wave] = sum;
    __syncthreads();
    float total = s_red[8];
    #pragma unroll
    for (int w2 = 1; w2 < 8; ++w2) total += s_red[8 + w2];

    alpha[(size_t)bt * SS + tid] = e * __builtin_amdgcn_rcpf(total);
}

// ---- Kernel 4: ctx = alpha @ enc via MFMA, bf16 out into cq[:, 0:512] ----
#define LDA_A 40
#define LDA_B 76
__global__ __launch_bounds__(256) void ctx_kernel(
    const float* __restrict__ alpha, const ushort_t* __restrict__ encB,
    const int* __restrict__ lens, ushort_t* __restrict__ cq)
{
    const int b = blockIdx.x;
    const int t0 = blockIdx.y * 16;
    const int h0 = blockIdx.z * 64;
    __shared__ ushort_t sA[16 * LDA_A];   // [t][s]
    __shared__ ushort_t sB[32 * LDA_B];   // [s][h]
    const int tid = threadIdx.x;
    const int lane = tid & 63, w = tid >> 6;
    const int quad = lane >> 4, lrow = lane & 15;
    const int nw = w * 16;
    const int len = lens[b];

    const int ar  = tid >> 4;          // 0..15  (t)
    const int ac2 = (tid & 15) * 2;    // 0..30  (s pair)
    const int br  = tid >> 3;          // 0..31  (s)
    const int bc8 = (tid & 7) * 8;     // h offset

    floatx4 acc = {0.f, 0.f, 0.f, 0.f};

    for (int s0 = 0; s0 < len; s0 += 32) {
        __syncthreads();
        {
            float2 a2 = *(const float2*)(alpha + (size_t)(b * TT + t0 + ar) * SS + s0 + ac2);
            uint_t pk = (uint_t)f2bf(a2.x) | ((uint_t)f2bf(a2.y) << 16);
            *(uint_t*)&sA[ar * LDA_A + ac2] = pk;
            uint4 ev = *(const uint4*)&encB[(size_t)(b * SS + s0 + br) * HD + h0 + bc8];
            *(uint4*)&sB[br * LDA_B + bc8] = ev;
        }
        __syncthreads();
        short8 af = *(const short8*)&sA[lrow * LDA_A + quad * 8];
        short8 bf;
        #pragma unroll
        for (int j = 0; j < 8; ++j)
            bf[j] = (short)sB[(quad * 8 + j) * LDA_B + nw + lrow];
        acc = __builtin_amdgcn_mfma_f32_16x16x32_bf16(af, bf, acc, 0, 0, 0);
    }
    #pragma unroll
    for (int r = 0; r < 4; ++r)
        cq[(size_t)(b * TT + t0 + quad * 4 + r) * 1024 + h0 + nw + lrow] = f2bf(acc[r]);
}

// ---- Kernel 5: out = tanh(cq @ WTo^T), MFMA, 32x64 tiles ----
__global__ __launch_bounds__(256) void out_kernel(
    const ushort_t* __restrict__ cq, const ushort_t* __restrict__ WTo,
    float* __restrict__ out)
{
    const int m0 = blockIdx.x * 32;
    const int n0 = blockIdx.y * 64;

    __shared__ ushort_t As[32 * LDP];     // [m][k]
    __shared__ ushort_t Bs[64 * LDP];     // [n][k]

    const int tid = threadIdx.x;
    const int lane = tid & 63, w = tid >> 6;
    const int quad = lane >> 4, lrow = lane & 15;
    const int mw = (w & 1) * 16, nw = (w >> 1) * 32;

    const int ar = tid >> 3, ac4 = (tid & 7) * 4;   // A: uint2 (4 u16)
    const int br = tid >> 2, bc8 = (tid & 3) * 8;   // B: uint4 (8 u16)

    floatx4 zero = {0.f, 0.f, 0.f, 0.f};
    floatx4 acc[2] = {zero, zero};

    uint2 av = *(const uint2*)&cq[(size_t)(m0 + ar) * 1024 + ac4];
    uint4 bv = *(const uint4*)&WTo[(size_t)(n0 + br) * 1024 + bc8];

    for (int k0 = 0; k0 < 1024; k0 += 32) {
        __syncthreads();
        *(uint2*)&As[ar * LDP + ac4] = av;
        *(uint4*)&Bs[br * LDP + bc8] = bv;
        __syncthreads();
        if (k0 + 32 < 1024) {
            av = *(const uint2*)&cq[(size_t)(m0 + ar) * 1024 + k0 + 32 + ac4];
            bv = *(const uint4*)&WTo[(size_t)(n0 + br) * 1024 + k0 + 32 + bc8];
        }
        short8 af = *(const short8*)&As[(mw + lrow) * LDP + quad * 8];
        #pragma unroll
        for (int j = 0; j < 2; ++j) {
            short8 bf8 = *(const short8*)&Bs[(nw + j * 16 + lrow) * LDP + quad * 8];
            acc[j] = __builtin_amdgcn_mfma_f32_16x16x32_bf16(af, bf8, acc[j], 0, 0, 0);
        }
    }
    #pragma unroll
    for (int j = 0; j < 2; ++j)
        #pragma unroll
        for (int r = 0; r < 4; ++r) {
            const int row = m0 + mw + quad * 4 + r;
            const int col = n0 + nw + j * 16 + lrow;
            out[(size_t)row * HD + col] = tanh_e(acc[j][r]);
        }
}

extern "C" void kernel_launch(void* const* d_in, const int* in_sizes, int n_in,
                              void* d_out, int out_size, void* d_ws, size_t ws_size,
                              hipStream_t stream) {
    (void)in_sizes; (void)n_in; (void)out_size; (void)ws_size;
    const float* query = (const float*)d_in[0];   // (B,T,H)
    const float* enc   = (const float*)d_in[1];   // (B,S,H)
    const int*   lens  = (const int*)d_in[2];     // (B,)
    const float* W_h   = (const float*)d_in[3];   // (H,H)
    const float* W_s   = (const float*)d_in[4];   // (H,H)
    const float* v     = (const float*)d_in[5];   // (H,)
    const float* W_out = (const float*)d_in[6];   // (2H,H)
    float* out = (float*)d_out;

    // workspace layout (~12 MB)
    ushort_t* WTs   = (ushort_t*)d_ws;                          // 512 KB
    ushort_t* WTh   = WTs + (size_t)HD * HD;                    // 512 KB
    ushort_t* WTo   = WTh + (size_t)HD * HD;                    // 1 MB
    ushort_t* encB  = WTo + (size_t)HD * 2 * HD;                // 2 MB (bf16 enc)
    float2*   tqa   = (float2*)(encB + (size_t)BB * SS * HD);   // 2 MB {tanh(pq), v*tanh(pq)}
    _Float16* peT   = (_Float16*)(tqa + (size_t)BB * TT * HD);  // 2 MB fp16 tanh(pe)^T
    _Float16* sp    = peT + (size_t)BB * HD * SS;               // 2 MB fp16 partials
    float*    alpha = (float*)(sp + (size_t)4 * BB * TT * SS);  // 1 MB
    ushort_t* cq    = (ushort_t*)(alpha + (size_t)BB * TT * SS);// 1 MB ([ctx|q] bf16)

    wtrans_kernel<<<dim3(1664), 256, 0, stream>>>(W_s, W_h, W_out, query, enc,
                                                  WTs, WTh, WTo, cq, encB);
    proj_kernel<<<dim3(40, 8), 256, 0, stream>>>(cq, encB, WTs, WTh, v, tqa, peT);
    score_part_kernel<<<dim3(BB * TT, 4), 256, 0, stream>>>(tqa, peT, v, lens, sp);
    combine_kernel<<<dim3(BB * TT), 512, 0, stream>>>(sp, lens, alpha);
    ctx_kernel<<<dim3(BB, TT / 16, HD / 64), 256, 0, stream>>>(alpha, encB, lens, cq);
    out_kernel<<<dim3(16, 8), 256, 0, stream>>>(cq, WTo, out);
}

// Round 7
// 125.367 us; speedup vs baseline: 1.2223x; 1.0267x over previous
//
#include <hip/hip_runtime.h>
#include <math.h>

#define HD 512
#define BB 4
#define TT 128
#define SS 512

typedef __attribute__((ext_vector_type(8))) short short8;
typedef __attribute__((ext_vector_type(4))) float floatx4;
typedef _Float16 half2_t __attribute__((ext_vector_type(2)));
typedef unsigned short ushort_t;
typedef unsigned int uint_t;

__device__ __forceinline__ float tanh_e(float x) {
    float t = __builtin_amdgcn_rcpf(__expf(2.f * x) + 1.f);
    return fmaf(-2.f, t, 1.f);
}
__device__ __forceinline__ ushort_t f2bf(float x) {      // RNE fp32->bf16
    unsigned int u = __float_as_uint(x);
    u += 0x7fffu + ((u >> 16) & 1u);
    return (ushort_t)(u >> 16);
}

// ---- Kernel 0: prep. W->bf16 [n][k] transposed (coalesced); query->cq right; enc->bf16 ----
// grid: 128 W-blocks (128k x 64n tiles) + 128 query blocks + 512 enc blocks = 768
__global__ __launch_bounds__(256) void wtrans_kernel(
    const float* __restrict__ Ws, const float* __restrict__ Wh,
    const float* __restrict__ Wo, const float* __restrict__ query,
    const float* __restrict__ enc,
    ushort_t* __restrict__ Ts, ushort_t* __restrict__ Th, ushort_t* __restrict__ To,
    ushort_t* __restrict__ cq, ushort_t* __restrict__ encB)
{
    const int bid = blockIdx.x;
    const int tid = threadIdx.x;
    if (bid < 128) {
        const float* src; ushort_t* dst; int K, l;
        if (bid < 32)      { src = Ws; dst = Ts; K = 512;  l = bid;      }
        else if (bid < 64) { src = Wh; dst = Th; K = 512;  l = bid - 32; }
        else               { src = Wo; dst = To; K = 1024; l = bid - 64; }
        const int ktiles = K >> 7;
        const int tk = l & (ktiles - 1), tn = l / ktiles;
        const int k0 = tk * 128, n0 = tn * 64;

        __shared__ ushort_t tile[64][136];     // [n][k], row 272B (16B aligned)

        const int lr  = tid >> 4;              // 0..15
        const int lc4 = (tid & 15) * 4;        // 0..60
        #pragma unroll
        for (int p = 0; p < 8; ++p) {
            const int row = p * 16 + lr;       // k-local
            float4 s = *(const float4*)(src + (size_t)(k0 + row) * HD + n0 + lc4);
            tile[lc4 + 0][row] = f2bf(s.x);
            tile[lc4 + 1][row] = f2bf(s.y);
            tile[lc4 + 2][row] = f2bf(s.z);
            tile[lc4 + 3][row] = f2bf(s.w);
        }
        __syncthreads();
        const int n = tid >> 2, kc = (tid & 3) * 32;
        #pragma unroll
        for (int j = 0; j < 4; ++j) {
            uint4 o = *(const uint4*)&tile[n][kc + j * 8];
            *(uint4*)&dst[(size_t)(n0 + n) * K + k0 + kc + j * 8] = o;
        }
    } else if (bid < 256) {
        // query -> bf16 into cq[m][512 + h]
        const int idx = ((bid - 128) * 256 + tid) * 8;
        const int m = idx >> 9, h = idx & 511;
        float4 q0 = *(const float4*)(query + (size_t)m * HD + h);
        float4 q1 = *(const float4*)(query + (size_t)m * HD + h + 4);
        uint4 o;
        o.x = (uint_t)f2bf(q0.x) | ((uint_t)f2bf(q0.y) << 16);
        o.y = (uint_t)f2bf(q0.z) | ((uint_t)f2bf(q0.w) << 16);
        o.z = (uint_t)f2bf(q1.x) | ((uint_t)f2bf(q1.y) << 16);
        o.w = (uint_t)f2bf(q1.z) | ((uint_t)f2bf(q1.w) << 16);
        *(uint4*)&cq[(size_t)m * 1024 + 512 + h] = o;
    } else {
        // enc -> bf16 encB (row-major)
        const size_t idx = ((size_t)(bid - 256) * 256 + tid) * 8;
        float4 e0 = *(const float4*)(enc + idx);
        float4 e1 = *(const float4*)(enc + idx + 4);
        uint4 o;
        o.x = (uint_t)f2bf(e0.x) | ((uint_t)f2bf(e0.y) << 16);
        o.y = (uint_t)f2bf(e0.z) | ((uint_t)f2bf(e0.w) << 16);
        o.z = (uint_t)f2bf(e1.x) | ((uint_t)f2bf(e1.y) << 16);
        o.w = (uint_t)f2bf(e1.z) | ((uint_t)f2bf(e1.w) << 16);
        *(uint4*)&encB[idx] = o;
    }
}

// ---- Kernel 1: MFMA proj. q-path: tqa = {tanh(pq), v*tanh(pq)} fp32.
//                           enc-path: peT = fp16(tanh(pe))^T per batch (B,H,S). ----
#define LDP 40
__global__ __launch_bounds__(256) void proj_kernel(
    const ushort_t* __restrict__ cq, const ushort_t* __restrict__ encB,
    const ushort_t* __restrict__ WTs, const ushort_t* __restrict__ WTh,
    const float* __restrict__ v,
    float2* __restrict__ tqa, _Float16* __restrict__ peT)
{
    const int bm = blockIdx.x;            // 0..39: 8 query tiles, 32 enc tiles
    const int bn = blockIdx.y;            // 0..7
    const bool isQ = (bm < 8);
    const ushort_t* A = isQ ? (cq + 512) : encB;
    const int lda = isQ ? 1024 : 512;
    const ushort_t* WT = isQ ? WTs : WTh;
    const int m0 = (isQ ? bm : bm - 8) * 64;
    const int n0 = bn * 64;

    __shared__ ushort_t As[64 * LDP];     // [m][k]
    __shared__ ushort_t Bs[64 * LDP];     // [n][k]

    const int tid = threadIdx.x;
    const int lane = tid & 63, w = tid >> 6;
    const int quad = lane >> 4, lrow = lane & 15;
    const int mw = (w & 1) * 32, nw = (w >> 1) * 32;

    const int ar = tid >> 2;              // 0..63
    const int ac = (tid & 3) * 8;         // 0,8,16,24

    floatx4 zero = {0.f, 0.f, 0.f, 0.f};
    floatx4 acc[2][2] = {{zero, zero}, {zero, zero}};

    uint4 ald = *(const uint4*)&A[(size_t)(m0 + ar) * lda + ac];
    uint4 bld = *(const uint4*)&WT[(size_t)(n0 + ar) * HD + ac];

    for (int k0 = 0; k0 < HD; k0 += 32) {
        __syncthreads();
        *(uint4*)&As[ar * LDP + ac] = ald;
        *(uint4*)&Bs[ar * LDP + ac] = bld;
        __syncthreads();
        if (k0 + 32 < HD) {
            ald = *(const uint4*)&A[(size_t)(m0 + ar) * lda + k0 + 32 + ac];
            bld = *(const uint4*)&WT[(size_t)(n0 + ar) * HD + k0 + 32 + ac];
        }
        short8 af[2], bf[2];
        #pragma unroll
        for (int i = 0; i < 2; ++i)
            af[i] = *(const short8*)&As[(mw + i * 16 + lrow) * LDP + quad * 8];
        #pragma unroll
        for (int j = 0; j < 2; ++j)
            bf[j] = *(const short8*)&Bs[(nw + j * 16 + lrow) * LDP + quad * 8];
        #pragma unroll
        for (int i = 0; i < 2; ++i)
            #pragma unroll
            for (int j = 0; j < 2; ++j)
                acc[i][j] = __builtin_amdgcn_mfma_f32_16x16x32_bf16(af[i], bf[j], acc[i][j], 0, 0, 0);
    }

    if (isQ) {
        #pragma unroll
        for (int j = 0; j < 2; ++j) {
            const int col = n0 + nw + j * 16 + lrow;
            const float vj = v[col];
            #pragma unroll
            for (int i = 0; i < 2; ++i)
                #pragma unroll
                for (int r = 0; r < 4; ++r) {
                    const int row = m0 + mw + i * 16 + quad * 4 + r;
                    float tq = tanh_e(acc[i][j][r]);
                    float2 o; o.x = tq; o.y = vj * tq;
                    tqa[(size_t)row * HD + col] = o;
                }
        }
    } else {
        #pragma unroll
        for (int i = 0; i < 2; ++i)
            #pragma unroll
            for (int j = 0; j < 2; ++j) {
                const int gm = m0 + mw + i * 16 + quad * 4;
                const int b = gm >> 9, s = gm & 511;
                const int col = n0 + nw + j * 16 + lrow;
                _Float16 t0 = (_Float16)tanh_e(acc[i][j][0]);
                _Float16 t1 = (_Float16)tanh_e(acc[i][j][1]);
                _Float16 t2 = (_Float16)tanh_e(acc[i][j][2]);
                _Float16 t3 = (_Float16)tanh_e(acc[i][j][3]);
                ushort4 o;
                o.x = *(ushort_t*)&t0; o.y = *(ushort_t*)&t1;
                o.z = *(ushort_t*)&t2; o.w = *(ushort_t*)&t3;
                *(ushort4*)((ushort_t*)peT + ((size_t)b * HD + col) * SS + s) = o;
            }
    }
}

// ---- Kernel 2: partial scores, tanh addition formula, paired-rcp.
//      grid (B*T, 4), 128 thr x 4 s.  term = v*(Tq+Te)/(1+Tq*Te). ----
__global__ __launch_bounds__(128) void score_part_kernel(
    const float2* __restrict__ tqa, const _Float16* __restrict__ peT,
    const float* __restrict__ vv, const int* __restrict__ lens,
    _Float16* __restrict__ sp)
{
    const int bt = blockIdx.x;
    const int hq = blockIdx.y;
    const int b = bt >> 7;
    const int tid = threadIdx.x;
    const int h0 = hq * 128;

    const int len = lens[b];
    const int s0 = tid * 4;
    if (s0 >= len) return;

    const float2* qa = tqa + (size_t)bt * HD + h0;       // wave-uniform -> SGPR
    const float* vp = vv + h0;                           // wave-uniform -> SGPR
    const ushort_t* col = (const ushort_t*)peT + ((size_t)b * HD + h0) * SS + s0;

    float acc[4] = {0.f, 0.f, 0.f, 0.f};
    #pragma unroll 4
    for (int h = 0; h < 128; h += 2) {
        uint2 pA = *(const uint2*)(col + (size_t)h * SS);
        uint2 pB = *(const uint2*)(col + (size_t)(h + 1) * SS);
        const float2 qA = qa[h], qB = qa[h + 1];
        const float vA = vp[h], vB = vp[h + 1];
        half2_t a01 = *(half2_t*)&pA.x, a23 = *(half2_t*)&pA.y;
        half2_t b01 = *(half2_t*)&pB.x, b23 = *(half2_t*)&pB.y;
        float teA[4] = {(float)a01[0], (float)a01[1], (float)a23[0], (float)a23[1]};
        float teB[4] = {(float)b01[0], (float)b01[1], (float)b23[0], (float)b23[1]};
        #pragma unroll
        for (int s = 0; s < 4; ++s) {
            float dA = fmaf(qA.x, teA[s], 1.f);
            float dB = fmaf(qB.x, teB[s], 1.f);
            float mA = fmaf(vA, teA[s], qA.y);
            float mB = fmaf(vB, teB[s], qB.y);
            float num = mA * dB;
            num = fmaf(mB, dA, num);
            acc[s] = fmaf(num, __builtin_amdgcn_rcpf(dA * dB), acc[s]);
        }
    }
    _Float16 f0 = (_Float16)acc[0], f1 = (_Float16)acc[1];
    _Float16 f2 = (_Float16)acc[2], f3 = (_Float16)acc[3];
    uint2 pk;
    pk.x = (uint_t)*(ushort_t*)&f0 | ((uint_t)*(ushort_t*)&f1 << 16);
    pk.y = (uint_t)*(ushort_t*)&f2 | ((uint_t)*(ushort_t*)&f3 << 16);
    *(uint2*)(sp + ((size_t)hq * (BB * TT) + bt) * SS + s0) = pk;
}

// ---- Kernel 3: combine partials + masked softmax -> alpha (zeros past len) ----
__global__ __launch_bounds__(512) void combine_kernel(
    const _Float16* __restrict__ sp, const int* __restrict__ lens,
    float* __restrict__ alpha)
{
    const int bt = blockIdx.x;
    const int b = bt >> 7;
    const int tid = threadIdx.x;
    const int wave = tid >> 6;
    __shared__ float s_red[16];

    const int len = lens[b];
    float sc = -INFINITY;
    if (tid < len) {
        const size_t i = (size_t)bt * SS + tid;
        const size_t st = (size_t)BB * TT * SS;
        sc = (float)sp[i] + (float)sp[i + st] + (float)sp[i + 2 * st] + (float)sp[i + 3 * st];
    }
    float m = sc;
    #pragma unroll
    for (int off = 32; off; off >>= 1) m = fmaxf(m, __shfl_xor(m, off, 64));
    if ((tid & 63) == 0) s_red[wave] = m;
    __syncthreads();
    m = s_red[0];
    #pragma unroll
    for (int w2 = 1; w2 < 8; ++w2) m = fmaxf(m, s_red[w2]);

    float e = (tid < len) ? __expf(sc - m) : 0.f;
    float sum = e;
    #pragma unroll
    for (int off = 32; off; off >>= 1) sum += __shfl_xor(sum, off, 64);
    if ((tid & 63) == 0) s_red[8 + wave] = sum;
    __syncthreads();
    float total = s_red[8];
    #pragma unroll
    for (int w2 = 1; w2 < 8; ++w2) total += s_red[8 + w2];

    alpha[(size_t)bt * SS + tid] = e * __builtin_amdgcn_rcpf(total);
}

// ---- Kernel 4: ctx = alpha @ enc via MFMA, bf16 out into cq[:, 0:512] ----
#define LDA_A 40
#define LDA_B 76
__global__ __launch_bounds__(256) void ctx_kernel(
    const float* __restrict__ alpha, const ushort_t* __restrict__ encB,
    const int* __restrict__ lens, ushort_t* __restrict__ cq)
{
    const int b = blockIdx.x;
    const int t0 = blockIdx.y * 16;
    const int h0 = blockIdx.z * 64;
    __shared__ ushort_t sA[16 * LDA_A];   // [t][s]
    __shared__ ushort_t sB[32 * LDA_B];   // [s][h]
    const int tid = threadIdx.x;
    const int lane = tid & 63, w = tid >> 6;
    const int quad = lane >> 4, lrow = lane & 15;
    const int nw = w * 16;
    const int len = lens[b];

    const int ar  = tid >> 4;          // 0..15  (t)
    const int ac2 = (tid & 15) * 2;    // 0..30  (s pair)
    const int br  = tid >> 3;          // 0..31  (s)
    const int bc8 = (tid & 7) * 8;     // h offset

    floatx4 acc = {0.f, 0.f, 0.f, 0.f};

    for (int s0 = 0; s0 < len; s0 += 32) {
        __syncthreads();
        {
            float2 a2 = *(const float2*)(alpha + (size_t)(b * TT + t0 + ar) * SS + s0 + ac2);
            uint_t pk = (uint_t)f2bf(a2.x) | ((uint_t)f2bf(a2.y) << 16);
            *(uint_t*)&sA[ar * LDA_A + ac2] = pk;
            uint4 ev = *(const uint4*)&encB[(size_t)(b * SS + s0 + br) * HD + h0 + bc8];
            *(uint4*)&sB[br * LDA_B + bc8] = ev;
        }
        __syncthreads();
        short8 af = *(const short8*)&sA[lrow * LDA_A + quad * 8];
        short8 bf;
        #pragma unroll
        for (int j = 0; j < 8; ++j)
            bf[j] = (short)sB[(quad * 8 + j) * LDA_B + nw + lrow];
        acc = __builtin_amdgcn_mfma_f32_16x16x32_bf16(af, bf, acc, 0, 0, 0);
    }
    #pragma unroll
    for (int r = 0; r < 4; ++r)
        cq[(size_t)(b * TT + t0 + quad * 4 + r) * 1024 + h0 + nw + lrow] = f2bf(acc[r]);
}

// ---- Kernel 5: out = tanh(cq @ WTo^T), MFMA, 32x32 tiles, 256 blocks ----
__global__ __launch_bounds__(256) void out_kernel(
    const ushort_t* __restrict__ cq, const ushort_t* __restrict__ WTo,
    float* __restrict__ out)
{
    const int m0 = blockIdx.x * 32;
    const int n0 = blockIdx.y * 32;

    __shared__ ushort_t As[32 * LDP];     // [m][k]
    __shared__ ushort_t Bs[32 * LDP];     // [n][k]

    const int tid = threadIdx.x;
    const int lane = tid & 63, w = tid >> 6;
    const int quad = lane >> 4, lrow = lane & 15;
    const int mw = (w & 1) * 16, nw = (w >> 1) * 16;

    const int r8 = tid >> 3, c4 = (tid & 7) * 4;   // uint2 (4 u16) per thread

    floatx4 acc = {0.f, 0.f, 0.f, 0.f};

    uint2 av = *(const uint2*)&cq[(size_t)(m0 + r8) * 1024 + c4];
    uint2 bv = *(const uint2*)&WTo[(size_t)(n0 + r8) * 1024 + c4];

    for (int k0 = 0; k0 < 1024; k0 += 32) {
        __syncthreads();
        *(uint2*)&As[r8 * LDP + c4] = av;
        *(uint2*)&Bs[r8 * LDP + c4] = bv;
        __syncthreads();
        if (k0 + 32 < 1024) {
            av = *(const uint2*)&cq[(size_t)(m0 + r8) * 1024 + k0 + 32 + c4];
            bv = *(const uint2*)&WTo[(size_t)(n0 + r8) * 1024 + k0 + 32 + c4];
        }
        short8 af = *(const short8*)&As[(mw + lrow) * LDP + quad * 8];
        short8 bf = *(const short8*)&Bs[(nw + lrow) * LDP + quad * 8];
        acc = __builtin_amdgcn_mfma_f32_16x16x32_bf16(af, bf, acc, 0, 0, 0);
    }
    #pragma unroll
    for (int r = 0; r < 4; ++r) {
        const int row = m0 + mw + quad * 4 + r;
        const int col = n0 + nw + lrow;
        out[(size_t)row * HD + col] = tanh_e(acc[r]);
    }
}

extern "C" void kernel_launch(void* const* d_in, const int* in_sizes, int n_in,
                              void* d_out, int out_size, void* d_ws, size_t ws_size,
                              hipStream_t stream) {
    (void)in_sizes; (void)n_in; (void)out_size; (void)ws_size;
    const float* query = (const float*)d_in[0];   // (B,T,H)
    const float* enc   = (const float*)d_in[1];   // (B,S,H)
    const int*   lens  = (const int*)d_in[2];     // (B,)
    const float* W_h   = (const float*)d_in[3];   // (H,H)
    const float* W_s   = (const float*)d_in[4];   // (H,H)
    const float* v     = (const float*)d_in[5];   // (H,)
    const float* W_out = (const float*)d_in[6];   // (2H,H)
    float* out = (float*)d_out;

    // workspace layout (~12 MB)
    ushort_t* WTs   = (ushort_t*)d_ws;                          // 512 KB
    ushort_t* WTh   = WTs + (size_t)HD * HD;                    // 512 KB
    ushort_t* WTo   = WTh + (size_t)HD * HD;                    // 1 MB
    ushort_t* encB  = WTo + (size_t)HD * 2 * HD;                // 2 MB (bf16 enc)
    float2*   tqa   = (float2*)(encB + (size_t)BB * SS * HD);   // 2 MB {tanh(pq), v*tanh(pq)}
    _Float16* peT   = (_Float16*)(tqa + (size_t)BB * TT * HD);  // 2 MB fp16 tanh(pe)^T
    _Float16* sp    = peT + (size_t)BB * HD * SS;               // 2 MB fp16 partials
    float*    alpha = (float*)(sp + (size_t)4 * BB * TT * SS);  // 1 MB
    ushort_t* cq    = (ushort_t*)(alpha + (size_t)BB * TT * SS);// 1 MB ([ctx|q] bf16)

    wtrans_kernel<<<dim3(768), 256, 0, stream>>>(W_s, W_h, W_out, query, enc,
                                                 WTs, WTh, WTo, cq, encB);
    proj_kernel<<<dim3(40, 8), 256, 0, stream>>>(cq, encB, WTs, WTh, v, tqa, peT);
    score_part_kernel<<<dim3(BB * TT, 4), 128, 0, stream>>>(tqa, peT, v, lens, sp);
    combine_kernel<<<dim3(BB * TT), 512, 0, stream>>>(sp, lens, alpha);
    ctx_kernel<<<dim3(BB, TT / 16, HD / 64), 256, 0, stream>>>(alpha, encB, lens, cq);
    out_kernel<<<dim3(16, 16), 256, 0, stream>>>(cq, WTo, out);
}